// Round 5
// baseline (105.487 us; speedup 1.0000x reference)
//
#include <hip/hip_runtime.h>
#include <hip/hip_bf16.h>
#include <cstdint>

typedef float f32x4 __attribute__((ext_vector_type(4)));
typedef short bf16x8 __attribute__((ext_vector_type(8)));

#define P_TOT 8192      // B*L
#define KH 768          // K*H (GEMM K-dim)
#define PADL 258        // padded sequence length (zero row before & after)
#define EPS_ 1e-5f

__device__ __forceinline__ unsigned short f2bf(float f) {
    unsigned int x = __float_as_uint(f);
    unsigned int r = (x + 0x7fffu + ((x >> 16) & 1u)) >> 16;
    return (unsigned short)r;
}

// ================= fused pre-kernel: embed (8192) | wtrans (288) | cumsum (32) =================
__global__ __launch_bounds__(256) void k_pre(
        const float* __restrict__ x, const float* __restrict__ pt, const float* __restrict__ et,
        const float* __restrict__ pbins, const float* __restrict__ ebins,
        const float* __restrict__ pemb, const float* __restrict__ eemb,
        const float* __restrict__ w1, const float* __restrict__ w2,
        const int* __restrict__ dur,
        unsigned short* __restrict__ xplain, unsigned short* __restrict__ xpplain,
        float* __restrict__ xpe, unsigned short* __restrict__ bt,
        int* __restrict__ cum, float* __restrict__ mel_len_out) {
    __shared__ char smem[16640];
    const int bx = blockIdx.x;
    const int t = threadIdx.x;

    if (bx < 8192) {
        // ---- embed role ----
        int p = bx, b = p >> 8, l = p & 255, f = t;
        float ptv = pt[p], etv = et[p];
        int lo = 0, hi = 255;
        while (lo < hi) { int mid = (lo + hi) >> 1; if (pbins[mid] < ptv) lo = mid + 1; else hi = mid; }
        int pidx = lo;
        lo = 0; hi = 255;
        while (lo < hi) { int mid = (lo + hi) >> 1; if (ebins[mid] < etv) lo = mid + 1; else hi = mid; }
        int eidx = lo;
        float xv = x[(size_t)p * 256 + f];
        float xpv = xv + pemb[(size_t)pidx * 256 + f];
        float xpev = xpv + eemb[(size_t)eidx * 256 + f];
        xpe[(size_t)p * 256 + f] = xpev;
        size_t row = (size_t)b * PADL + 1 + l;
        xplain [row * 256 + f] = f2bf(xv);
        xpplain[row * 256 + f] = f2bf(xpv);
        if (l == 0)   { xplain[((size_t)b * PADL) * 256 + f] = 0;       xpplain[((size_t)b * PADL) * 256 + f] = 0; }
        if (l == 255) { xplain[((size_t)b * PADL + 257) * 256 + f] = 0; xpplain[((size_t)b * PADL + 257) * 256 + f] = 0; }
    } else if (bx < 8480) {
        // ---- weight transpose role ----
        float (*tile)[65] = (float(*)[65])smem;
        int id = bx - 8192;
        int tf = id & 3; int th = (id >> 2) & 3;
        int rest = id >> 4;
        int k = rest % 3; rest /= 3;
        int set = rest % 3; int tensor = rest / 3;
        const float* src = tensor ? w2 : w1;
        const float* s = src + (((size_t)set * 3 + k) * 256 + th * 64) * 256 + tf * 64;
        int fl = t & 63;
        int q = t >> 6;
#pragma unroll
        for (int i = 0; i < 16; ++i) {
            int hl = i * 4 + q;
            tile[hl][fl] = s[(size_t)hl * 256 + fl];
        }
        __syncthreads();
        size_t rowbase = (size_t)tensor * 768 + set * 256 + tf * 64;
        size_t colbase = (size_t)k * 256 + th * 64;
#pragma unroll
        for (int i = 0; i < 16; ++i) {
            int f2 = i * 4 + q;
            bt[(rowbase + f2) * KH + colbase + fl] = f2bf(tile[fl][f2]);
        }
    } else {
        // ---- cumsum role ----
        int* sh = (int*)smem;
        int b = bx - 8480;
        int l = t;
        sh[l] = dur[b * 256 + l];
        for (int s = 1; s < 256; s <<= 1) {
            __syncthreads();
            int add = (l >= s) ? sh[l - s] : 0;
            __syncthreads();
            sh[l] += add;
        }
        __syncthreads();
        cum[b * 256 + l] = sh[l];
        if (l == 0) mel_len_out[b] = (float)sh[255];
    }
}

// ================= conv GEMM helpers (32-row x 256-col tile, BK=32) =================
// A: plain padded bf16 [B][PADL][256]; browPad = b*PADL + l0 ; step kt: tap=kt>>8, hc=kt&255
__device__ __forceinline__ void stage32(const unsigned short* __restrict__ A,
                                        const unsigned short* __restrict__ Bm,
                                        int browPad, int kt,
                                        unsigned short* As, unsigned short* Bs, int tid) {
    const int tap = kt >> 8, hc = kt & 255;
    if (tid < 128) {
        const int ar = tid >> 2;
        const int ac = (tid & 3) * 8;
        __builtin_amdgcn_global_load_lds(
            (const __attribute__((address_space(1))) unsigned int*)(A + (size_t)(browPad + tap + ar) * 256 + hc + ac),
            (__attribute__((address_space(3))) unsigned int*)(As + tid * 8), 16, 0, 0);
    }
    const int br = tid >> 2;
    const int bc = (tid & 3) * 8;
#pragma unroll
    for (int j = 0; j < 4; ++j)
        __builtin_amdgcn_global_load_lds(
            (const __attribute__((address_space(1))) unsigned int*)(Bm + (size_t)(j * 64 + br) * KH + kt + bc),
            (__attribute__((address_space(3))) unsigned int*)(Bs + j * 2048 + tid * 8), 16, 0, 0);
}

__device__ __forceinline__ void compute32(const unsigned short* As, const unsigned short* Bs,
                                          int lane, int wc, f32x4 acc[2][4]) {
    const int rsel = lane & 15;
    const int kof = (lane >> 4) * 8;
    bf16x8 af[2], bfr[4];
#pragma unroll
    for (int m = 0; m < 2; ++m)
        af[m] = *(const bf16x8*)(As + (size_t)(m * 16 + rsel) * 32 + kof);
#pragma unroll
    for (int n = 0; n < 4; ++n)
        bfr[n] = *(const bf16x8*)(Bs + (size_t)(wc * 64 + n * 16 + rsel) * 32 + kof);
#pragma unroll
    for (int m = 0; m < 2; ++m)
#pragma unroll
        for (int n = 0; n < 4; ++n)
            acc[m][n] = __builtin_amdgcn_mfma_f32_16x16x32_bf16(af[m], bfr[n], acc[m][n], 0, 0, 0);
}

// ================= conv1 + bias + relu + LN -> padded bf16 h =================
__global__ __launch_bounds__(256) void k_conv_ln1(
        const unsigned short* __restrict__ xplain, const unsigned short* __restrict__ xpplain,
        const unsigned short* __restrict__ bt,
        const float* __restrict__ b1, const float* __restrict__ g1, const float* __restrict__ be1,
        unsigned short* __restrict__ h0, unsigned short* __restrict__ h1, unsigned short* __restrict__ h2) {
    __shared__ unsigned short As[2][1024];
    __shared__ unsigned short Bs[2][8192];
    __shared__ float2 red[4][32];

    const int pred = blockIdx.y;
    const unsigned short* A  = (pred < 2) ? xplain : xpplain;
    const unsigned short* Bm = bt + (size_t)pred * 256 * KH;
    unsigned short* hout = (pred == 0) ? h0 : (pred == 1) ? h1 : h2;

    const int rowBase = blockIdx.x * 32;
    const int bb = rowBase >> 8;
    const int l0 = rowBase & 255;
    const int browPad = bb * PADL + l0;
    const int tid = threadIdx.x;
    const int lane = tid & 63;
    const int wc = tid >> 6;
    const int rsel = lane & 15;
    const int lhi = lane >> 4;

    f32x4 acc[2][4];
#pragma unroll
    for (int m = 0; m < 2; ++m)
#pragma unroll
        for (int n = 0; n < 4; ++n) acc[m][n] = (f32x4){0.f, 0.f, 0.f, 0.f};

    stage32(A, Bm, browPad, 0, As[0], Bs[0], tid);
    __syncthreads();
    int cur = 0;
    for (int kt = 32; kt < KH; kt += 32) {
        stage32(A, Bm, browPad, kt, As[cur ^ 1], Bs[cur ^ 1], tid);
        compute32(As[cur], Bs[cur], lane, wc, acc);
        __syncthreads();
        cur ^= 1;
    }
    compute32(As[cur], Bs[cur], lane, wc, acc);

    float bcol[4], gcol[4], becol[4];
#pragma unroll
    for (int n = 0; n < 4; ++n) {
        int c = wc * 64 + n * 16 + rsel;
        bcol[n] = b1[pred * 256 + c];
        gcol[n] = g1[pred * 256 + c];
        becol[n] = be1[pred * 256 + c];
    }

#pragma unroll
    for (int m = 0; m < 2; ++m)
#pragma unroll
        for (int r = 0; r < 4; ++r) {
            float s = 0.f, s2 = 0.f;
#pragma unroll
            for (int n = 0; n < 4; ++n) {
                float v = fmaxf(acc[m][n][r] + bcol[n], 0.f);
                s += v; s2 += v * v;
            }
#pragma unroll
            for (int o = 1; o < 16; o <<= 1) { s += __shfl_xor(s, o); s2 += __shfl_xor(s2, o); }
            if (rsel == 0) red[wc][m * 16 + lhi * 4 + r] = make_float2(s, s2);
        }
    __syncthreads();
    if (tid < 32) {
        float2 a0 = red[0][tid], a1 = red[1][tid], a2 = red[2][tid], a3 = red[3][tid];
        red[0][tid] = make_float2(a0.x + a1.x + a2.x + a3.x, a0.y + a1.y + a2.y + a3.y);
    }
    __syncthreads();

#pragma unroll
    for (int m = 0; m < 2; ++m)
#pragma unroll
        for (int r = 0; r < 4; ++r) {
            int rl = m * 16 + lhi * 4 + r;
            float2 t = red[0][rl];
            float mean = t.x * (1.f / 256.f);
            float var = t.y * (1.f / 256.f) - mean * mean;
            float inv = rsqrtf(var + EPS_);
            int l = l0 + rl;
            size_t row = (size_t)bb * PADL + 1 + l;
#pragma unroll
            for (int n = 0; n < 4; ++n) {
                float v = fmaxf(acc[m][n][r] + bcol[n], 0.f);
                float h = (v - mean) * inv * gcol[n] + becol[n];
                int c = wc * 64 + n * 16 + rsel;
                hout[row * 256 + c] = f2bf(h);
                if (l == 0)   hout[((size_t)bb * PADL) * 256 + c] = 0;
                if (l == 255) hout[((size_t)bb * PADL + 257) * 256 + c] = 0;
            }
        }
}

// ================= fused conv2+LN+proj (768 blocks) | gather (4096 blocks) =================
__global__ __launch_bounds__(256) void k_conv2_gather(
        const unsigned short* __restrict__ h0, const unsigned short* __restrict__ h1,
        const unsigned short* __restrict__ h2, const unsigned short* __restrict__ bt,
        const float* __restrict__ b2, const float* __restrict__ g2, const float* __restrict__ be2,
        const float* __restrict__ wl, const float* __restrict__ bl,
        const char* __restrict__ mask,
        const float* __restrict__ xpe, const int* __restrict__ cum,
        float* __restrict__ outp, float* __restrict__ out, float* __restrict__ maskout) {
    __shared__ char smem[38912];
    const int bx = blockIdx.x;
    const int tid = threadIdx.x;

    if (bx < 768) {
        // ---- conv2 role ----
        unsigned short (*As)[1024] = (unsigned short(*)[1024])smem;
        unsigned short (*Bs)[8192] = (unsigned short(*)[8192])(smem + 4096);
        float2 (*red)[32] = (float2(*)[32])(smem + 36864);
        float  (*red2)[32] = (float(*)[32])(smem + 37888);

        const int pred = bx >> 8;
        const int px = bx & 255;
        const unsigned short* A  = (pred == 0) ? h0 : (pred == 1) ? h1 : h2;
        const unsigned short* Bm = bt + (size_t)(768 + pred * 256) * KH;

        const int rowBase = px * 32;
        const int bb = rowBase >> 8;
        const int l0 = rowBase & 255;
        const int browPad = bb * PADL + l0;
        const int lane = tid & 63;
        const int wc = tid >> 6;
        const int rsel = lane & 15;
        const int lhi = lane >> 4;

        f32x4 acc[2][4];
#pragma unroll
        for (int m = 0; m < 2; ++m)
#pragma unroll
            for (int n = 0; n < 4; ++n) acc[m][n] = (f32x4){0.f, 0.f, 0.f, 0.f};

        stage32(A, Bm, browPad, 0, As[0], Bs[0], tid);
        __syncthreads();
        int cur = 0;
        for (int kt = 32; kt < KH; kt += 32) {
            stage32(A, Bm, browPad, kt, As[cur ^ 1], Bs[cur ^ 1], tid);
            compute32(As[cur], Bs[cur], lane, wc, acc);
            __syncthreads();
            cur ^= 1;
        }
        compute32(As[cur], Bs[cur], lane, wc, acc);

        float bcol[4], gcol[4], becol[4], wcol[4];
#pragma unroll
        for (int n = 0; n < 4; ++n) {
            int c = wc * 64 + n * 16 + rsel;
            bcol[n] = b2[pred * 256 + c];
            gcol[n] = g2[pred * 256 + c];
            becol[n] = be2[pred * 256 + c];
            wcol[n] = wl[pred * 256 + c];
        }

#pragma unroll
        for (int m = 0; m < 2; ++m)
#pragma unroll
            for (int r = 0; r < 4; ++r) {
                float s = 0.f, s2 = 0.f;
#pragma unroll
                for (int n = 0; n < 4; ++n) {
                    float v = fmaxf(acc[m][n][r] + bcol[n], 0.f);
                    s += v; s2 += v * v;
                }
#pragma unroll
                for (int o = 1; o < 16; o <<= 1) { s += __shfl_xor(s, o); s2 += __shfl_xor(s2, o); }
                if (rsel == 0) red[wc][m * 16 + lhi * 4 + r] = make_float2(s, s2);
            }
        __syncthreads();
        if (tid < 32) {
            float2 a0 = red[0][tid], a1 = red[1][tid], a2 = red[2][tid], a3 = red[3][tid];
            red[0][tid] = make_float2(a0.x + a1.x + a2.x + a3.x, a0.y + a1.y + a2.y + a3.y);
        }
        __syncthreads();

#pragma unroll
        for (int m = 0; m < 2; ++m)
#pragma unroll
            for (int r = 0; r < 4; ++r) {
                int rl = m * 16 + lhi * 4 + r;
                float2 t = red[0][rl];
                float mean = t.x * (1.f / 256.f);
                float var = t.y * (1.f / 256.f) - mean * mean;
                float inv = rsqrtf(var + EPS_);
                float d = 0.f;
#pragma unroll
                for (int n = 0; n < 4; ++n) {
                    float v = fmaxf(acc[m][n][r] + bcol[n], 0.f);
                    float h = (v - mean) * inv * gcol[n] + becol[n];
                    d += h * wcol[n];
                }
#pragma unroll
                for (int o = 1; o < 16; o <<= 1) d += __shfl_xor(d, o);
                if (rsel == 0) red2[wc][rl] = d;
            }
        __syncthreads();
        if (tid < 32) {
            int p = rowBase + tid;
            float o = red2[0][tid] + red2[1][tid] + red2[2][tid] + red2[3][tid] + bl[pred];
            if (mask[p]) o = 0.f;
            outp[(size_t)pred * P_TOT + p] = o;
        }
    } else {
        // ---- gather role ----
        int* sc = (int*)smem;
        int g = bx - 768;
        int b = g >> 7;
        int t0 = (g & 127) * 16;
        sc[tid] = cum[b * 256 + tid];
        __syncthreads();
        int mel = sc[255];
        int wv = tid >> 6, lane = tid & 63;
#pragma unroll
        for (int it = 0; it < 4; ++it) {
            int t = t0 + it * 4 + wv;
            int lo = 0, hi = 256;
            while (lo < hi) { int mid = (lo + hi) >> 1; if (sc[mid] <= t) lo = mid + 1; else hi = mid; }
            bool valid = t < mel;
            int idx = lo > 255 ? 255 : lo;
            f32x4 v = (f32x4){0.f, 0.f, 0.f, 0.f};
            if (valid) v = *(const f32x4*)(xpe + ((size_t)(b * 256 + idx)) * 256 + lane * 4);
            *(f32x4*)(out + ((size_t)(b * 2048 + t)) * 256 + lane * 4) = v;
            if (lane == 0) maskout[b * 2048 + t] = valid ? 0.f : 1.f;
        }
    }
}

extern "C" void kernel_launch(void* const* d_in, const int* in_sizes, int n_in,
                              void* d_out, int out_size, void* d_ws, size_t ws_size,
                              hipStream_t stream) {
    const float* x     = (const float*)d_in[0];
    const float* pt    = (const float*)d_in[1];
    const float* et    = (const float*)d_in[2];
    const float* w1    = (const float*)d_in[3];
    const float* b1    = (const float*)d_in[4];
    const float* g1    = (const float*)d_in[5];
    const float* be1   = (const float*)d_in[6];
    const float* w2    = (const float*)d_in[7];
    const float* b2    = (const float*)d_in[8];
    const float* g2    = (const float*)d_in[9];
    const float* be2   = (const float*)d_in[10];
    const float* wl    = (const float*)d_in[11];
    const float* bl    = (const float*)d_in[12];
    const float* pbins = (const float*)d_in[13];
    const float* ebins = (const float*)d_in[14];
    const float* pemb  = (const float*)d_in[15];
    const float* eemb  = (const float*)d_in[16];
    const char*  mask  = (const char*)d_in[17];
    const int*   dur   = (const int*)d_in[18];

    char* ws = (char*)d_ws;
    // padded plain buffers: 32*258*256*2B = 4,227,072 B each
    unsigned short* xplain  = (unsigned short*)(ws + 0);
    unsigned short* xpplain = (unsigned short*)(ws + 8388608);
    unsigned short* h0      = (unsigned short*)(ws + 16777216);
    unsigned short* h1      = (unsigned short*)(ws + 25165824);
    unsigned short* h2      = (unsigned short*)(ws + 33554432);
    float*          xpe     = (float*)(ws + 41943040);
    unsigned short* btall   = (unsigned short*)(ws + 52428800);
    int*            cum     = (int*)(ws + 56623104);

    float* out        = (float*)d_out;
    float* out_pred   = out + 16777216;           // log_dur | pitch | energy (8192 each)
    float* out_mellen = out + 16801792;
    float* out_mask   = out + 16801824;

    hipLaunchKernelGGL(k_pre, dim3(8512), dim3(256), 0, stream,
                       x, pt, et, pbins, ebins, pemb, eemb, w1, w2, dur,
                       xplain, xpplain, xpe, btall, cum, out_mellen);

    hipLaunchKernelGGL(k_conv_ln1, dim3(256, 3), dim3(256), 0, stream,
                       xplain, xpplain, btall, b1, g1, be1, h0, h1, h2);

    hipLaunchKernelGGL(k_conv2_gather, dim3(4864), dim3(256), 0, stream,
                       h0, h1, h2, btall, b2, g2, be2, wl, bl, mask,
                       xpe, cum, out_pred, out, out_mask);
}